// Round 1
// baseline (923.127 us; speedup 1.0000x reference)
//
#include <hip/hip_runtime.h>

#define MDIM 64

// ---------------- Kernel 1: partial Gram matrices G = X^T X ----------------
// grid.x = nblk, 256 threads. Block b processes rows [b*rpb, min(N,(b+1)*rpb)),
// writes its 64x64 partial G to partials + b*4096.
__global__ __launch_bounds__(256) void k_gram(const float* __restrict__ X,
                                              float* __restrict__ partials,
                                              int N, int rpb) {
  __shared__ float xs[64][68];   // pad 68 floats: keeps b128 16B-aligned, conflict-free
  const int t  = threadIdx.x;
  const int tr = t >> 4;         // 0..15  (tile row /4)
  const int tc = t & 15;         // 0..15  (tile col /4)

  float acc[4][4];
#pragma unroll
  for (int i = 0; i < 4; ++i)
#pragma unroll
    for (int j = 0; j < 4; ++j) acc[i][j] = 0.f;

  long row0   = (long)blockIdx.x * rpb;
  long rowEnd = row0 + rpb;
  if (rowEnd > N) rowEnd = N;

  for (long r0 = row0; r0 < rowEnd; r0 += 64) {
    // stage 64 rows (64*64 floats) coalesced: 4 rounds of 256 float4
#pragma unroll
    for (int it = 0; it < 4; ++it) {
      int idx = it * 256 + t;        // float4 index 0..1023
      int rr  = idx >> 4;            // row 0..63
      int cq  = idx & 15;            // quad 0..15
      long gr = r0 + rr;
      float4 v = make_float4(0.f, 0.f, 0.f, 0.f);
      if (gr < rowEnd) v = *reinterpret_cast<const float4*>(X + gr * MDIM + cq * 4);
      *reinterpret_cast<float4*>(&xs[rr][cq * 4]) = v;   // zero-pad OOB rows
    }
    __syncthreads();

#pragma unroll 8
    for (int r = 0; r < 64; ++r) {
      float a4[4], b4[4];
      *reinterpret_cast<float4*>(a4) = *reinterpret_cast<const float4*>(&xs[r][tr * 4]);
      *reinterpret_cast<float4*>(b4) = *reinterpret_cast<const float4*>(&xs[r][tc * 4]);
#pragma unroll
      for (int i = 0; i < 4; ++i)
#pragma unroll
        for (int j = 0; j < 4; ++j) acc[i][j] += a4[i] * b4[j];
    }
    __syncthreads();
  }

  float* p = partials + (long)blockIdx.x * 4096;
#pragma unroll
  for (int i = 0; i < 4; ++i) {
    float4 v = make_float4(acc[i][0], acc[i][1], acc[i][2], acc[i][3]);
    *reinterpret_cast<float4*>(p + (tr * 4 + i) * 64 + tc * 4) = v;
  }
}

// ---------------- Kernel 2: reduce partials -> G ----------------
__global__ __launch_bounds__(256) void k_reduce(const float* __restrict__ partials,
                                                float* __restrict__ G, int nblk) {
  int e = blockIdx.x * 256 + threadIdx.x;   // 0..4095
  float s = 0.f;
  for (int b = 0; b < nblk; ++b) s += partials[(long)b * 4096 + e];
  G[e] = s;
}

// ---------------- Kernel 3: Cholesky G = L L^T, then Rinv = (L^-1)^T ----------------
__global__ __launch_bounds__(64) void k_cholinv(const float* __restrict__ G,
                                                float* __restrict__ Rinv) {
  __shared__ float A[64][65];
  __shared__ float Li[64][65];
  const int t = threadIdx.x;

  for (int j = 0; j < 64; ++j) A[t][j] = G[t * 64 + j];
  __syncthreads();

  for (int k = 0; k < 64; ++k) {
    if (t == k) A[k][k] = sqrtf(A[k][k]);
    __syncthreads();
    if (t > k) A[t][k] = A[t][k] / A[k][k];
    __syncthreads();
    if (t > k) {
      float lik = A[t][k];
      for (int j = k + 1; j <= t; ++j) A[t][j] -= lik * A[j][k];
    }
    __syncthreads();
  }

  // thread t computes column t of Linv (lower-triangular inverse)
  Li[t][t] = 1.f / A[t][t];
  for (int r = t + 1; r < 64; ++r) {
    float s = 0.f;
    for (int k2 = t; k2 < r; ++k2) s += A[r][k2] * Li[k2][t];
    Li[r][t] = -s / A[r][r];
  }
  __syncthreads();

  // Rinv (upper) : Rinv[k][j] = Linv[j][k]; zeros below diagonal
  for (int j = 0; j < 64; ++j)
    Rinv[t * 64 + j] = (j >= t) ? Li[j][t] : 0.f;
}

// ---------------- Kernel 4: Q = X * Rinv ----------------
// 128 rows/block, 128 threads; thread tile = 4 rows x 16 cols.
__global__ __launch_bounds__(128) void k_apply(const float* __restrict__ X,
                                               const float* __restrict__ RinvG,
                                               float* __restrict__ Q, int N) {
  __shared__ float xs[128][65];   // pad 65: x-reads conflict-free (16 distinct banks)
  __shared__ float rs[64][64];    // Rinv; reads are quad-broadcast, 2-way max (free)
  const int t = threadIdx.x;

  // load Rinv (4096 floats, linear float4)
#pragma unroll
  for (int i = 0; i < 8; ++i) {
    int idx = i * 128 + t;   // 0..1023
    reinterpret_cast<float4*>(&rs[0][0])[idx] =
        reinterpret_cast<const float4*>(RinvG)[idx];
  }

  long r0 = (long)blockIdx.x * 128;
  // stage 128 rows coalesced (scalar LDS stores due to pad-65 alignment)
#pragma unroll
  for (int i = 0; i < 16; ++i) {
    int idx = i * 128 + t;   // float4 index 0..2047
    int rr  = idx >> 4;
    int cq  = idx & 15;
    long gr = r0 + rr;
    float4 v = make_float4(0.f, 0.f, 0.f, 0.f);
    if (gr < N) v = *reinterpret_cast<const float4*>(X + gr * 64 + cq * 4);
    xs[rr][cq * 4 + 0] = v.x;
    xs[rr][cq * 4 + 1] = v.y;
    xs[rr][cq * 4 + 2] = v.z;
    xs[rr][cq * 4 + 3] = v.w;
  }
  __syncthreads();

  const int rowg  = t >> 2;        // 0..31
  const int colg  = t & 3;         // 0..3
  const int rbase = rowg * 4;
  const int cbase = colg * 16;

  float acc[4][16];
#pragma unroll
  for (int i = 0; i < 4; ++i)
#pragma unroll
    for (int j = 0; j < 16; ++j) acc[i][j] = 0.f;

#pragma unroll 4
  for (int k = 0; k < 64; ++k) {
    float b[16];
    *reinterpret_cast<float4*>(&b[0])  = *reinterpret_cast<const float4*>(&rs[k][cbase]);
    *reinterpret_cast<float4*>(&b[4])  = *reinterpret_cast<const float4*>(&rs[k][cbase + 4]);
    *reinterpret_cast<float4*>(&b[8])  = *reinterpret_cast<const float4*>(&rs[k][cbase + 8]);
    *reinterpret_cast<float4*>(&b[12]) = *reinterpret_cast<const float4*>(&rs[k][cbase + 12]);
    float xv[4];
#pragma unroll
    for (int i = 0; i < 4; ++i) xv[i] = xs[rbase + i][k];
#pragma unroll
    for (int i = 0; i < 4; ++i)
#pragma unroll
      for (int j = 0; j < 16; ++j) acc[i][j] += xv[i] * b[j];
  }

#pragma unroll
  for (int i = 0; i < 4; ++i) {
    long gr = r0 + rbase + i;
    if (gr < N) {
#pragma unroll
      for (int q = 0; q < 4; ++q) {
        float4 v = make_float4(acc[i][q * 4 + 0], acc[i][q * 4 + 1],
                               acc[i][q * 4 + 2], acc[i][q * 4 + 3]);
        *reinterpret_cast<float4*>(Q + gr * 64 + cbase + q * 4) = v;
      }
    }
  }
}

extern "C" void kernel_launch(void* const* d_in, const int* in_sizes, int n_in,
                              void* d_out, int out_size, void* d_ws, size_t ws_size,
                              hipStream_t stream) {
  const float* X = (const float*)d_in[0];
  float* Q = (float*)d_out;
  const int N = in_sizes[0] / MDIM;

  float* ws       = (float*)d_ws;
  float* G        = ws;            // 4096 floats
  float* Rinv     = ws + 4096;     // 4096 floats
  float* partials = ws + 8192;

  long avail = ((long)(ws_size / 4) - 8192) / 4096;   // how many partial tiles fit
  int nblk = (avail >= 512) ? 512 : (int)(avail < 1 ? 1 : avail);
  int rpb = (N + nblk - 1) / nblk;

  k_gram<<<nblk, 256, 0, stream>>>(X, partials, N, rpb);
  k_reduce<<<16, 256, 0, stream>>>(partials, G, nblk);
  k_cholinv<<<1, 64, 0, stream>>>(G, Rinv);

  int nb3 = (N + 127) / 128;
  k_apply<<<nb3, 128, 0, stream>>>(X, Rinv, Q, N);
}